// Round 1
// baseline (341.966 us; speedup 1.0000x reference)
//
#include <hip/hip_runtime.h>
#include <math.h>

#define BATCH 16384
#define KN 32       // neighbors
#define DF 128      // feature dim
#define NM 4        // masks

// One block per batch row. 128 threads:
//   f  = t & 31  -> which float4 chunk of the 128-float feature row
//   kb = t >> 5  -> which group of 8 neighbors this thread accumulates
// Each half-wave (32 lanes) loads one full 512B embed row as 32x float4
// (16B/lane, fully coalesced). 8 independent gathers in flight per thread.
__global__ __launch_bounds__(128) void wagg_kernel(
    const float* __restrict__ embed,
    const int*   __restrict__ nidx,
    const float* __restrict__ nw,
    float*       __restrict__ out)
{
    const int b = blockIdx.x;
    const int t = threadIdx.x;

    __shared__ float wn[NM][KN];   // weight powers: 1, sqrt(w), w, w*sqrt(w)
    __shared__ int   sidx[KN];

    if (t < KN) {
        const float wv = nw[b * KN + t];
        const float sq = sqrtf(wv);
        wn[0][t] = 1.0f;
        wn[1][t] = sq;
        wn[2][t] = wv;
        wn[3][t] = wv * sq;
        sidx[t]  = nidx[b * KN + t];
    }
    __syncthreads();

    // Per-mask inverse row sums (LDS broadcasts; trivial vs. gather cost).
    float inv[NM];
    #pragma unroll
    for (int j = 0; j < NM; ++j) {
        float s = 0.0f;
        #pragma unroll
        for (int k = 0; k < KN; ++k) s += wn[j][k];
        inv[j] = 1.0f / s;
    }

    const int f  = t & 31;
    const int kb = t >> 5;

    float4 acc[NM];
    #pragma unroll
    for (int j = 0; j < NM; ++j) { acc[j].x = acc[j].y = acc[j].z = acc[j].w = 0.0f; }

    #pragma unroll
    for (int kk = 0; kk < 8; ++kk) {
        const int k = kb * 8 + kk;
        const size_t row = (size_t)sidx[k];
        const float4 v = *((const float4*)(embed + row * DF) + f);
        #pragma unroll
        for (int j = 0; j < NM; ++j) {
            const float wj = wn[j][k];
            acc[j].x += wj * v.x;
            acc[j].y += wj * v.y;
            acc[j].z += wj * v.z;
            acc[j].w += wj * v.w;
        }
    }

    // Cross k-group reduction through LDS: part[kb][j][f]
    __shared__ float4 part[4][NM][32];
    #pragma unroll
    for (int j = 0; j < NM; ++j) part[kb][j][f] = acc[j];
    __syncthreads();

    // Thread t now produces output float4 index t of row b:
    //   j = t>>5 (mask), f = t&31 -> out[b][j*128 + f*4 .. +3]
    const int jo = t >> 5;
    float4 r;
    r.x = part[0][jo][f].x + part[1][jo][f].x + part[2][jo][f].x + part[3][jo][f].x;
    r.y = part[0][jo][f].y + part[1][jo][f].y + part[2][jo][f].y + part[3][jo][f].y;
    r.z = part[0][jo][f].z + part[1][jo][f].z + part[2][jo][f].z + part[3][jo][f].z;
    r.w = part[0][jo][f].w + part[1][jo][f].w + part[2][jo][f].w + part[3][jo][f].w;

    const float s = inv[jo];
    r.x *= s; r.y *= s; r.z *= s; r.w *= s;

    ((float4*)(out + (size_t)b * (NM * DF)))[t] = r;
}

extern "C" void kernel_launch(void* const* d_in, const int* in_sizes, int n_in,
                              void* d_out, int out_size, void* d_ws, size_t ws_size,
                              hipStream_t stream) {
    const float* embed = (const float*)d_in[0];   // [500000, 128] f32
    const int*   nidx  = (const int*)  d_in[1];   // [16384, 32] i32
    const float* nw    = (const float*)d_in[2];   // [16384, 32] f32
    float* out = (float*)d_out;                   // [16384, 512] f32

    wagg_kernel<<<BATCH, 128, 0, stream>>>(embed, nidx, nw, out);
}

// Round 2
// 339.529 us; speedup vs baseline: 1.0072x; 1.0072x over previous
//
#include <hip/hip_runtime.h>
#include <math.h>

#define BATCH 16384
#define KN 32       // neighbors
#define DF 128      // feature dim
#define NM 4        // masks
#define RPB 8       // batch rows per block (256 threads / 32)

// Block = 256 threads = 8 batch rows x 32 threads.
// Thread (r, f): r = t>>5 batch row within block, f = t&31 float4 chunk.
// Each thread accumulates ALL 32 neighbors for its chunk: 32 independent
// coalesced float4 gathers in flight, no cross-thread reduction.
__global__ __launch_bounds__(256, 4) void wagg_kernel(
    const float* __restrict__ embed,
    const int*   __restrict__ nidx,
    const float* __restrict__ nw,
    float*       __restrict__ out)
{
    const int t  = threadIdx.x;
    const int r  = t >> 5;   // row within block
    const int f  = t & 31;   // float4 chunk / staging k
    const int b  = blockIdx.x * RPB + r;

    __shared__ float4 wq[RPB][KN];    // (1, sqrt(w), w, w*sqrt(w))
    __shared__ int    sidx[RPB][KN];
    __shared__ float4 sinv[RPB];      // per-row 1/sum for each mask

    // ---- staging: thread (r, f) handles neighbor k=f of row b ----
    {
        const float w  = nw[(size_t)b * KN + f];
        const float sq = sqrtf(w);
        float4 q;
        q.x = 1.0f; q.y = sq; q.z = w; q.w = w * sq;
        wq[r][f]   = q;
        sidx[r][f] = nidx[(size_t)b * KN + f];

        // butterfly reduce over the 32 k-lanes (masks < 32 stay within the
        // 32-lane half of the wave64, which holds exactly one row's k's)
        float4 s = q;
        #pragma unroll
        for (int m = 1; m < 32; m <<= 1) {
            s.x += __shfl_xor(s.x, m);
            s.y += __shfl_xor(s.y, m);
            s.z += __shfl_xor(s.z, m);
            s.w += __shfl_xor(s.w, m);
        }
        if (f == 0) {
            float4 iv;
            iv.x = 1.0f / s.x;   // == 1/32 exactly
            iv.y = 1.0f / s.y;
            iv.z = 1.0f / s.z;
            iv.w = 1.0f / s.w;
            sinv[r] = iv;
        }
    }
    __syncthreads();

    // ---- gather + weighted accumulate ----
    float4 a0, a1, a2, a3;
    a0.x=a0.y=a0.z=a0.w=0.f;
    a1.x=a1.y=a1.z=a1.w=0.f;
    a2.x=a2.y=a2.z=a2.w=0.f;
    a3.x=a3.y=a3.z=a3.w=0.f;

    #pragma unroll
    for (int k = 0; k < KN; ++k) {
        const int    row = sidx[r][k];                       // LDS broadcast
        const float4 q   = wq[r][k];                         // LDS broadcast
        const float4 v   = *((const float4*)(embed + (size_t)row * DF) + f);
        a0.x += v.x;        a0.y += v.y;        a0.z += v.z;        a0.w += v.w;
        a1.x += q.y * v.x;  a1.y += q.y * v.y;  a1.z += q.y * v.z;  a1.w += q.y * v.w;
        a2.x += q.z * v.x;  a2.y += q.z * v.y;  a2.z += q.z * v.z;  a2.w += q.z * v.w;
        a3.x += q.w * v.x;  a3.y += q.w * v.y;  a3.z += q.w * v.z;  a3.w += q.w * v.w;
    }

    const float4 iv = sinv[r];
    a0.x *= iv.x; a0.y *= iv.x; a0.z *= iv.x; a0.w *= iv.x;
    a1.x *= iv.y; a1.y *= iv.y; a1.z *= iv.y; a1.w *= iv.y;
    a2.x *= iv.z; a2.y *= iv.z; a2.z *= iv.z; a2.w *= iv.z;
    a3.x *= iv.w; a3.y *= iv.w; a3.z *= iv.w; a3.w *= iv.w;

    // out row b: [mask j][128 floats]; thread writes chunk f of each mask
    float4* o = (float4*)(out + (size_t)b * (NM * DF));
    o[0 * 32 + f] = a0;
    o[1 * 32 + f] = a1;
    o[2 * 32 + f] = a2;
    o[3 * 32 + f] = a3;
}

extern "C" void kernel_launch(void* const* d_in, const int* in_sizes, int n_in,
                              void* d_out, int out_size, void* d_ws, size_t ws_size,
                              hipStream_t stream) {
    const float* embed = (const float*)d_in[0];   // [500000, 128] f32
    const int*   nidx  = (const int*)  d_in[1];   // [16384, 32] i32
    const float* nw    = (const float*)d_in[2];   // [16384, 32] f32
    float* out = (float*)d_out;                   // [16384, 512] f32

    wagg_kernel<<<BATCH / RPB, 256, 0, stream>>>(embed, nidx, nw, out);
}